// Round 12
// baseline (417.548 us; speedup 1.0000x reference)
//
#include <hip/hip_runtime.h>
#include <cstddef>
#include <cstdint>

#define NE 100000   // entities
#define EN 4096     // new edges
#define ET 254096   // total edges
#define D 128       // D_ENT
#define DR 64       // D_REL
#define NR 9        // relations
#define NT 3        // node types
#define NI 8        // intents
#define TE 256      // edges per pass1 tile
#define TILES_X 28  // blocks per relation (252 total ~ 1/CU)

using frag  = __attribute__((ext_vector_type(8))) short;
using f32x4 = __attribute__((ext_vector_type(4))) float;
using u32x4 = __attribute__((ext_vector_type(4))) unsigned int;

__device__ __forceinline__ ushort f2b(float x) {
  union { float f; uint32_t u; } v; v.f = x;
  uint32_t r = v.u + 0x7FFFu + ((v.u >> 16) & 1u);  // RNE
  return (ushort)(r >> 16);
}

// pack two f32 -> one u32 of 2xbf16 (RNE) in a single instruction
__device__ __forceinline__ uint32_t cvtpk(float lo, float hi) {
  uint32_t r;
  asm("v_cvt_pk_bf16_f32 %0, %1, %2" : "=v"(r) : "v"(lo), "v"(hi));
  return r;
}

// LDS tiles: row-major [rows][128] bf16, 16B chunks XOR-swizzled by (row&7).
__device__ __forceinline__ frag lds_rd(const ushort* b, int row, int k) {
  const int ch = ((k >> 3) ^ (row & 7));
  return *(const frag*)(b + row * D + (ch << 3));
}
__device__ __forceinline__ void lds_wr(ushort* b, int row, int ch, frag v) {
  *(frag*)(b + row * D + ((ch ^ (row & 7)) << 3)) = v;
}
__device__ __forceinline__ void lds_wr2(ushort* b, int row, int k, uint32_t v) {
  const int ch = (k >> 3) ^ (row & 7);               // k even, pair (k,k+1)
  *(uint32_t*)(b + row * D + (ch << 3) + (k & 7)) = v;
}

__global__ void k_init(ushort* __restrict__ entb, const int* __restrict__ ntypes,
                       const float* __restrict__ def, const float* __restrict__ emb) {
  int i = blockIdx.x * blockDim.x + threadIdx.x;  // one per 4 elems
  if (i >= NE * (D / 4)) return;
  int row = i >> 5, ch = i & 31;
  float4 v;
  if (row < EN) v = ((const float4*)(def + ntypes[row] * D))[ch];
  else v = ((const float4*)(emb + (size_t)(row - EN) * D))[ch];
  ushort4 h;
  h.x = f2b(v.x); h.y = f2b(v.y); h.z = f2b(v.z); h.w = f2b(v.w);
  ((ushort4*)entb)[i] = h;
}

__global__ void k_zero_cnt(int* cnt) { if (threadIdx.x < 48) cnt[threadIdx.x] = 0; }

// ---------- weights -> bf16, transposed [n][k], pre-swizzled to the LDS image ----------
__global__ __launch_bounds__(256) void k_wconv(const float* __restrict__ Wr,
                                               const float* __restrict__ Wm,
                                               ushort* __restrict__ wrelb,
                                               ushort* __restrict__ wmsgb) {
  const int nrel = NR * DR * (D / 8);   // 9216 chunks
  const int nmsg = NR * D * (D / 8);    // 18432 chunks
  int idx = blockIdx.x * 256 + threadIdx.x;
  if (idx < nrel) {
    int r = idx / (DR * 16), rem = idx % (DR * 16), n = rem / 16, sc = rem % 16;
    int kb = (sc ^ (n & 7)) * 8;
    const float* s = Wr + (size_t)r * D * DR + (size_t)kb * DR + n;
    uint4 pk;
    pk.x = cvtpk(s[0 * DR], s[1 * DR]); pk.y = cvtpk(s[2 * DR], s[3 * DR]);
    pk.z = cvtpk(s[4 * DR], s[5 * DR]); pk.w = cvtpk(s[6 * DR], s[7 * DR]);
    *(uint4*)(wrelb + (size_t)r * DR * D + n * D + sc * 8) = pk;
  } else if (idx < nrel + nmsg) {
    int j = idx - nrel;
    int r = j / (D * 16), rem = j % (D * 16), n = rem / 16, sc = rem % 16;
    int kb = (sc ^ (n & 7)) * 8;
    const float* s = Wm + (size_t)r * D * D + (size_t)kb * D + n;
    uint4 pk;
    pk.x = cvtpk(s[0 * D], s[1 * D]); pk.y = cvtpk(s[2 * D], s[3 * D]);
    pk.z = cvtpk(s[4 * D], s[5 * D]); pk.w = cvtpk(s[6 * D], s[7 * D]);
    *(uint4*)(wmsgb + (size_t)r * D * D + n * D + sc * 8) = pk;
  }
}

// ---------- fused histograms ----------
__global__ __launch_bounds__(256) void k_hist2(const int* __restrict__ nedg,
                                               const int* __restrict__ sedg,
                                               int* __restrict__ cnt,
                                               int* __restrict__ thist) {
  __shared__ int h[NR];
  if (threadIdx.x < NR) h[threadIdx.x] = 0;
  __syncthreads();
  int e = blockIdx.x * 256 + threadIdx.x;
  if (e < ET) {
    const int* p = (e < EN) ? nedg + (size_t)e * 5 : sedg + (size_t)(e - EN) * 5;
    atomicAdd(&h[p[4]], 1);
    atomicAdd(&thist[p[2]], 1);
  }
  __syncthreads();
  if (threadIdx.x < NR && h[threadIdx.x]) atomicAdd(&cnt[threadIdx.x], h[threadIdx.x]);
}

__global__ void k_prefix(const int* __restrict__ cnt, int* __restrict__ base,
                         int* __restrict__ head) {
  if (threadIdx.x == 0) {
    int acc = 0;
    for (int r = 0; r < NR; r++) { base[r] = acc; head[r] = acc; acc += cnt[r]; }
  }
}

// ---------- target prefix scan ----------
__global__ __launch_bounds__(256) void k_scan1(const int* __restrict__ hist,
                                               int* __restrict__ local_ex,
                                               int* __restrict__ bsum, int n) {
  __shared__ int s[256];
  int i = blockIdx.x * 256 + threadIdx.x;
  int v = (i < n) ? hist[i] : 0;
  s[threadIdx.x] = v;
  __syncthreads();
  for (int off = 1; off < 256; off <<= 1) {
    int t = (threadIdx.x >= off) ? s[threadIdx.x - off] : 0;
    __syncthreads();
    s[threadIdx.x] += t;
    __syncthreads();
  }
  if (i < n) local_ex[i] = s[threadIdx.x] - v;
  if (threadIdx.x == 255) bsum[blockIdx.x] = s[255];
}

__global__ __launch_bounds__(512) void k_scan2(int* __restrict__ bsum, int nb) {
  __shared__ int s[512];
  int v = (threadIdx.x < nb) ? bsum[threadIdx.x] : 0;
  s[threadIdx.x] = v;
  __syncthreads();
  for (int off = 1; off < 512; off <<= 1) {
    int t = (threadIdx.x >= off) ? s[threadIdx.x - off] : 0;
    __syncthreads();
    s[threadIdx.x] += t;
    __syncthreads();
  }
  if (threadIdx.x < nb) bsum[threadIdx.x] = s[threadIdx.x] - v;
}

__global__ void k_scan3(int* __restrict__ tgt_off, const int* __restrict__ bsum,
                        int* __restrict__ thead) {
  int i = blockIdx.x * 256 + threadIdx.x;
  if (i < NE) {
    int v = tgt_off[i] + bsum[i >> 8];
    tgt_off[i] = v;
    thead[i] = v;
  }
  if (i == 0) tgt_off[NE] = ET;
}

// ---------- fused scatter: bucket-ordered epack{src, iw_index, tpos} + sequential tp2 ----------
__global__ __launch_bounds__(256) void k_scatter3(const int* __restrict__ nedg,
                                                  const int* __restrict__ sedg,
                                                  int* __restrict__ head,
                                                  int* __restrict__ thead,
                                                  int4* __restrict__ epack,
                                                  int2* __restrict__ tp2) {
  __shared__ int h[NR], bb[NR];
  if (threadIdx.x < NR) h[threadIdx.x] = 0;
  __syncthreads();
  int e = blockIdx.x * 256 + threadIdx.x;
  int r = -1, pos = 0, s = 0, t = 0, tt = 0;
  if (e < ET) {
    const int* p = (e < EN) ? nedg + (size_t)e * 5 : sedg + (size_t)(e - EN) * 5;
    s = p[0]; t = p[2]; tt = p[3]; r = p[4];
    pos = atomicAdd(&h[r], 1);
  }
  __syncthreads();
  if (threadIdx.x < NR)
    bb[threadIdx.x] = h[threadIdx.x] ? atomicAdd(&head[threadIdx.x], h[threadIdx.x]) : 0;
  __syncthreads();
  if (r >= 0) {
    int pt = atomicAdd(&thead[t], 1);
    epack[bb[r] + pos] = make_int4(s, (t * NT + tt) * NR, pt, 0);
    tp2[e] = make_int2(pt, t);   // sequential by e (coalesced)
  }
}

// ---------- per-layer dense precompute: IW[t][tt][r] for all entities ----------
__global__ __launch_bounds__(1024) void k_iw(
    const ushort* __restrict__ entb,
    const float* __restrict__ W_int, const float* __restrict__ b_int,
    const float* __restrict__ W_ibn, const float* __restrict__ b_ibn,
    float* __restrict__ IW) {
  __shared__ ushort sE[256 * D];         // 64 KB, swizzled; reused as fp32 staging
  __shared__ ushort sWi[NT * 16 * D];    // 12 KB: W_int^T, rows 8..15 zero
  __shared__ float sInt3[256 * 25];      // [row][tt*8+j], stride 25
  __shared__ float sbint[NT * NI], sWibn[NT * NI * NR], sbibn[NT * NR];

  const int tid = threadIdx.x;
  const int lane = tid & 63, wv = tid >> 6, g = lane >> 4, c = lane & 15;

  {  // two-phase W_int staging
    float a[2], b[2];
#pragma unroll
    for (int j = 0; j < 2; j++) {
      int i = tid + j * 1024;
      if (i < NT * NI * (D / 2)) {
        int tt = i / (NI * D / 2), rem = i % (NI * D / 2), jj = rem / (D / 2), k2 = rem % (D / 2);
        const float* Wi = W_int + (size_t)tt * D * NI;
        a[j] = Wi[(2 * k2) * NI + jj]; b[j] = Wi[(2 * k2 + 1) * NI + jj];
      }
    }
#pragma unroll
    for (int j = 0; j < 2; j++) {
      int i = tid + j * 1024;
      if (i < NT * NI * (D / 2)) {
        int tt = i / (NI * D / 2), rem = i % (NI * D / 2), jj = rem / (D / 2), k2 = rem % (D / 2);
        lds_wr2(sWi, tt * 16 + jj, 2 * k2, cvtpk(a[j], b[j]));
      }
    }
  }
  for (int i = tid; i < NT * 8 * (D / 2); i += 1024) {
    int tt = i / (8 * D / 2), rem = i % (8 * D / 2), j = rem / (D / 2), k2 = rem % (D / 2);
    lds_wr2(sWi, tt * 16 + 8 + j, 2 * k2, 0u);
  }
  if (tid < NT * NI) sbint[tid] = b_int[tid];
  for (int i = tid; i < NT * NI * NR; i += 1024) sWibn[i] = W_ibn[i];
  if (tid < NT * NR) sbibn[tid] = b_ibn[tid];

  const int ebase = blockIdx.x * 256;
  const int nrow = min(256, NE - ebase);
  {
    frag tmp[4];
#pragma unroll
    for (int j = 0; j < 4; j++) {
      int i = tid + j * 1024, row = i >> 4, ch = i & 15;
      tmp[j] = (row < nrow) ? ((const frag*)(entb + (size_t)(ebase + row) * D))[ch] : (frag){};
    }
#pragma unroll
    for (int j = 0; j < 4; j++) {
      int i = tid + j * 1024, row = i >> 4, ch = i & 15;
      lds_wr(sE, row, ch, tmp[j]);
    }
  }
  __syncthreads();

  {
    f32x4 accI[NT];
#pragma unroll
    for (int tt = 0; tt < NT; tt++) accI[tt] = (f32x4){0.f, 0.f, 0.f, 0.f};
#pragma unroll
    for (int ks = 0; ks < 4; ks++) {
      const int k = ks * 32 + g * 8;
      frag a = lds_rd(sE, wv * 16 + c, k);
#pragma unroll
      for (int tt = 0; tt < NT; tt++) {
        frag b = lds_rd(sWi, tt * 16 + c, k);
        accI[tt] = __builtin_amdgcn_mfma_f32_16x16x32_bf16(a, b, accI[tt], 0, 0, 0);
      }
    }
    if (c < NI) {
      const int rb = wv * 16 + g * 4;
#pragma unroll
      for (int tt = 0; tt < NT; tt++)
#pragma unroll
        for (int q = 0; q < 4; q++) sInt3[(rb + q) * 25 + tt * 8 + c] = accI[tt][q];
    }
  }
  __syncthreads();

  float* stg = (float*)sE;
  {
    const int row = tid & 255, tt = tid >> 8;
    if (tt < NT && row < nrow) {
      float it[NI], mx = -1e30f;
#pragma unroll
      for (int j = 0; j < NI; j++) {
        it[j] = sInt3[row * 25 + tt * 8 + j] + sbint[tt * NI + j];
        mx = fmaxf(mx, it[j]);
      }
      float ssum = 0.f;
#pragma unroll
      for (int j = 0; j < NI; j++) { it[j] = __expf(it[j] - mx); ssum += it[j]; }
      const float inv = 1.f / ssum;
      float qv[NR];
#pragma unroll
      for (int k = 0; k < NR; k++) qv[k] = sbibn[tt * NR + k];
#pragma unroll
      for (int j = 0; j < NI; j++) {
        const float ij = it[j] * inv;
#pragma unroll
        for (int k = 0; k < NR; k++) qv[k] = fmaf(ij, sWibn[(tt * NI + j) * NR + k], qv[k]);
      }
      float m9 = qv[0];
#pragma unroll
      for (int k = 1; k < NR; k++) m9 = fmaxf(m9, qv[k]);
      float s9 = 0.f;
#pragma unroll
      for (int k = 0; k < NR; k++) s9 += __expf(qv[k] - m9);
      const float i9 = 1.f / s9;
#pragma unroll
      for (int k = 0; k < NR; k++) stg[row * 27 + tt * 9 + k] = __expf(qv[k] - m9) * i9;
    }
  }
  __syncthreads();

  const int n27 = nrow * 27;
  float* outp = IW + (size_t)ebase * 27;
  for (int i = tid; i < n27; i += 1024) outp[i] = stg[i];
}

// ---------- per-edge pass: epack + cross-tile register prefetch + NT msg stores ----------
__global__ __launch_bounds__(1024) void k_pass1(
    const ushort* __restrict__ entb,
    const int4* __restrict__ epack,
    const int* __restrict__ cnt, const int* __restrict__ base_g,
    const float* __restrict__ IW,
    const float* __restrict__ rel_emb, const float* __restrict__ b_rel,
    const ushort* __restrict__ wrelb, const ushort* __restrict__ wmsgb,
    ushort* __restrict__ msgbuf, float* __restrict__ exps_s) {
  const int r = blockIdx.y;
  __shared__ ushort sA[TE * D];          // 64 KB: src tile (bf16, swizzled)
  __shared__ ushort sWm[D * D];          // 32 KB
  __shared__ ushort sWr[DR * D];         // 16 KB
  __shared__ int sTP[TE];
  __shared__ float sIW[TE];
  __shared__ float sbrel[DR], srele[DR];

  const int tid = threadIdx.x;
  const int lane = tid & 63;
  const int wv = tid >> 6;       // 0..15
  const int g = lane >> 4;       // 0..3
  const int c = lane & 15;       // 0..15
  const int row = tid & 255, h = tid >> 8;

  // weight staging: straight b128 copies of the pre-swizzled bf16 image
  {
    const frag* wr = (const frag*)(wrelb + (size_t)r * DR * D);
    ((frag*)sWr)[tid] = wr[tid];                       // 1024 chunks exactly
    const frag* wm = (const frag*)(wmsgb + (size_t)r * D * D);
    ((frag*)sWm)[tid] = wm[tid];
    ((frag*)sWm)[tid + 1024] = wm[tid + 1024];
  }
  if (tid < DR) { sbrel[tid] = b_rel[r * DR + tid]; srele[tid] = rel_emb[r * DR + tid]; }

  const int nr = cnt[r];
  const int bbase = base_g[r];
  const int ntiles = (nr + TE - 1) / TE;

  int4 mp; frag tmp[4]; float iwv = 0.f;
  auto prefetch = [&](int t_) {
    int eidx = t_ * TE + row;
    if (eidx >= nr) eidx = 0;                          // clamp within relation
    mp = epack[bbase + eidx];
    const frag* rp = (const frag*)(entb + (size_t)mp.x * D);
#pragma unroll
    for (int j = 0; j < 4; j++) tmp[j] = rp[h * 4 + j];
    iwv = IW[mp.y + r];
  };

  int tile = blockIdx.x;
  if (tile < ntiles) prefetch(tile);

  for (; tile < ntiles; tile += gridDim.x) {
    const int ne = min(TE, nr - tile * TE);
    __syncthreads();  // prev tile's GEMM/epilogue done with sA/sTP/sIW (and staging on iter 0)

    // commit staged tile
#pragma unroll
    for (int j = 0; j < 4; j++) lds_wr(sA, row, h * 4 + j, tmp[j]);
    if (h == 0) { sTP[row] = mp.z; sIW[row] = iwv; }
    __syncthreads();

    // prefetch next tile (hides under GEMM + epilogue)
    const int nxt = tile + gridDim.x;
    if (nxt < ntiles) prefetch(nxt);

    // ---- main GEMMs ----
    f32x4 accR[4], accM[8];
#pragma unroll
    for (int nt = 0; nt < 4; nt++) accR[nt] = (f32x4){0.f, 0.f, 0.f, 0.f};
#pragma unroll
    for (int nt = 0; nt < 8; nt++) accM[nt] = (f32x4){0.f, 0.f, 0.f, 0.f};
#pragma unroll
    for (int ks = 0; ks < 4; ks++) {
      const int k = ks * 32 + g * 8;
      frag a0 = lds_rd(sA, wv * 16 + c, k);
#pragma unroll
      for (int nt = 0; nt < 4; nt++) {
        frag b = lds_rd(sWr, nt * 16 + c, k);
        accR[nt] = __builtin_amdgcn_mfma_f32_16x16x32_bf16(a0, b, accR[nt], 0, 0, 0);
      }
#pragma unroll
      for (int nt = 0; nt < 8; nt++) {
        frag b = lds_rd(sWm, nt * 16 + c, k);
        accM[nt] = __builtin_amdgcn_mfma_f32_16x16x32_bf16(a0, b, accM[nt], 0, 0, 0);
      }
    }

    const int mb = wv * 16 + g * 4;

    // ---- score epilogue ----
    float es[4];
    {
      float v[4] = {0.f, 0.f, 0.f, 0.f};
#pragma unroll
      for (int nt = 0; nt < 4; nt++) {
        const int col = nt * 16 + c;
        const float br = sbrel[col], re = srele[col];
#pragma unroll
        for (int q = 0; q < 4; q++) {
          const float x = accR[nt][q] + br;
          const float sl = x > 0.f ? 1.0507009873554805f * x
                                   : 1.7580993408473766f * (__expf(x) - 1.f);
          v[q] = fmaf(sl, re, v[q]);
        }
      }
#pragma unroll
      for (int off = 1; off < 16; off <<= 1)
#pragma unroll
        for (int q = 0; q < 4; q++) v[q] += __shfl_xor(v[q], off, 64);
#pragma unroll
      for (int q = 0; q < 4; q++) {
        const int m = mb + q;
        es[q] = __expf(v[q] * sIW[m]);
        if (c == 0 && m < ne) __builtin_nontemporal_store(es[q], &exps_s[sTP[m]]);
      }
    }

    // ---- msg write: NT stores (bypass L2 -> no thrash of exps/entb/IW) ----
    {
#pragma unroll
      for (int q = 0; q < 4; q++) {
        const int m = mb + q;
        ushort* mrow = msgbuf + (size_t)sTP[m] * D;
#pragma unroll
        for (int nt = 0; nt < 8; nt++) {
          float val = accM[nt][q] * es[q];
          float other = __shfl_xor(val, 1, 64);
          if (!(c & 1) && m < ne)
            __builtin_nontemporal_store(cvtpk(val, other), (uint32_t*)(mrow + nt * 16 + c));
        }
      }
    }
  }
}

// ---------- per-target reduce: NT msgbuf loads; writes ent + drec (both coalesced) ----------
__global__ __launch_bounds__(256) void k_agg(
    const ushort* __restrict__ msgbuf, const float* __restrict__ exps_s,
    const int* __restrict__ tgt_off,
    ushort* __restrict__ entb, float* __restrict__ fout,
    float* __restrict__ drec, int last) {
  const int lg = threadIdx.x & 15;
  const int grp = threadIdx.x >> 4;
  const int ngrp = gridDim.x * 16;
  for (int t = blockIdx.x * 16 + grp; t < NE; t += ngrp) {
    const int beg = tgt_off[t], end = tgt_off[t + 1];
    float a[8] = {0.f, 0.f, 0.f, 0.f, 0.f, 0.f, 0.f, 0.f};
    float dsum = 0.f;
    for (int j = beg; j < end; j++) {
      const u32x4 pk = __builtin_nontemporal_load((const u32x4*)(msgbuf + (size_t)j * D + lg * 8));
      dsum += exps_s[j];
      a[0] += __uint_as_float(pk.x << 16); a[1] += __uint_as_float(pk.x & 0xFFFF0000u);
      a[2] += __uint_as_float(pk.y << 16); a[3] += __uint_as_float(pk.y & 0xFFFF0000u);
      a[4] += __uint_as_float(pk.z << 16); a[5] += __uint_as_float(pk.z & 0xFFFF0000u);
      a[6] += __uint_as_float(pk.w << 16); a[7] += __uint_as_float(pk.w & 0xFFFF0000u);
    }
    const float rec = (dsum != 0.f) ? 1.f / dsum : 0.f;
    if (lg == 0) drec[t] = rec;
#pragma unroll
    for (int i = 0; i < 8; i++) a[i] *= rec;
    if (last) {
      float4* o = (float4*)(fout + (size_t)t * D + lg * 8);
      o[0] = make_float4(a[0], a[1], a[2], a[3]);
      o[1] = make_float4(a[4], a[5], a[6], a[7]);
    } else {
      uint4 pk;
      pk.x = (uint32_t)f2b(a[0]) | ((uint32_t)f2b(a[1]) << 16);
      pk.y = (uint32_t)f2b(a[2]) | ((uint32_t)f2b(a[3]) << 16);
      pk.z = (uint32_t)f2b(a[4]) | ((uint32_t)f2b(a[5]) << 16);
      pk.w = (uint32_t)f2b(a[6]) | ((uint32_t)f2b(a[7]) << 16);
      *(uint4*)(entb + (size_t)t * D + lg * 8) = pk;
    }
  }
}

// ---------- dist in original edge order: sequential reads of tp2, sequential writes ----------
__global__ __launch_bounds__(256) void k_dist2(const int2* __restrict__ tp2,
                                               const float* __restrict__ exps_s,
                                               const float* __restrict__ drec,
                                               float* __restrict__ dout) {
  int e = blockIdx.x * 256 + threadIdx.x;
  if (e >= ET) return;
  const int2 v = tp2[e];
  dout[e] = exps_s[v.x] * drec[v.y];
}

extern "C" void kernel_launch(void* const* d_in, const int* in_sizes, int n_in,
                              void* d_out, int out_size, void* d_ws, size_t ws_size,
                              hipStream_t stream) {
  const int* nedg = (const int*)d_in[0];
  const int* ntypes = (const int*)d_in[1];
  const int* sedg = (const int*)d_in[2];
  const float* emb = (const float*)d_in[3];
  const float* def = (const float*)d_in[4];
  const float* rel_emb = (const float*)d_in[5];
  const float* W_rel = (const float*)d_in[6];
  const float* b_rel = (const float*)d_in[7];
  const float* W_msg = (const float*)d_in[8];
  const float* W_int = (const float*)d_in[9];
  const float* b_int = (const float*)d_in[10];
  const float* W_ibn = (const float*)d_in[11];
  const float* b_ibn = (const float*)d_in[12];
  float* out = (float*)d_out;

  char* w = (char*)d_ws;
  size_t off = 0;
  ushort* entb = (ushort*)(w + off); off += (size_t)NE * D * 2;        // 25.6 MB
  ushort* msgbuf = (ushort*)(w + off); off += (size_t)ET * D * 2;      // 65.0 MB
  float* exps_s = (float*)(w + off); off += (size_t)ET * 4;
  int4* epack = (int4*)(w + off); off += (size_t)ET * 16;              // 4.1 MB
  int2* tp2 = (int2*)(w + off); off += (size_t)ET * 8;                 // 2.0 MB
  int* tgt_off = (int*)(w + off); off += (size_t)(NE + 4) * 4;
  int* thead = (int*)(w + off); off += (size_t)NE * 4;
  int* thist = (int*)(w + off); off += (size_t)NE * 4;
  float* drec = (float*)(w + off); off += (size_t)NE * 4;
  int* bsum = (int*)(w + off); off += 2048;
  int* cnt = (int*)(w + off); off += 192;
  float* IW = (float*)(w + off); off += (size_t)NE * NT * NR * 4;      // 10.8 MB
  ushort* wrelb = (ushort*)(w + off); off += (size_t)NR * DR * D * 2;  // 147 KB
  ushort* wmsgb = (ushort*)(w + off); off += (size_t)NR * D * D * 2;   // 295 KB
  int* base_g = cnt + 16;
  int* head = cnt + 32;
  float* dist_base = out + (size_t)NE * D;

  const int eblocks = (ET + 255) / 256;
  const int nb = (NE + 255) / 256;  // 391 scan/iw blocks
  const int wblocks = (NR * DR * (D / 8) + NR * D * (D / 8) + 255) / 256;

  k_init<<<dim3((NE * (D / 4) + 255) / 256), 256, 0, stream>>>(entb, ntypes, def, emb);
  k_zero_cnt<<<1, 64, 0, stream>>>(cnt);
  (void)hipMemsetAsync(thist, 0, (size_t)NE * 4, stream);
  k_wconv<<<dim3(wblocks), 256, 0, stream>>>(W_rel, W_msg, wrelb, wmsgb);
  k_hist2<<<dim3(eblocks), 256, 0, stream>>>(nedg, sedg, cnt, thist);
  k_prefix<<<1, 64, 0, stream>>>(cnt, base_g, head);
  k_scan1<<<dim3(nb), 256, 0, stream>>>(thist, tgt_off, bsum, NE);
  k_scan2<<<1, 512, 0, stream>>>(bsum, nb);
  k_scan3<<<dim3(nb), 256, 0, stream>>>(tgt_off, bsum, thead);
  k_scatter3<<<dim3(eblocks), 256, 0, stream>>>(nedg, sedg, head, thead, epack, tp2);

  for (int l = 0; l < 3; l++) {
    k_iw<<<dim3(nb), 1024, 0, stream>>>(entb, W_int, b_int, W_ibn, b_ibn, IW);
    k_pass1<<<dim3(TILES_X, NR), 1024, 0, stream>>>(
        entb, epack, cnt, base_g, IW, rel_emb, b_rel, wrelb, wmsgb, msgbuf, exps_s);
    k_agg<<<dim3(2048), 256, 0, stream>>>(msgbuf, exps_s, tgt_off, entb, out, drec, l == 2);
    k_dist2<<<dim3(eblocks), 256, 0, stream>>>(tp2, exps_s, drec,
                                               dist_base + (size_t)l * ET);
  }
}

// Round 13
// 339.995 us; speedup vs baseline: 1.2281x; 1.2281x over previous
//
#include <hip/hip_runtime.h>
#include <cstddef>
#include <cstdint>

#define NE 100000   // entities
#define EN 4096     // new edges
#define ET 254096   // total edges
#define D 128       // D_ENT
#define DR 64       // D_REL
#define NR 9        // relations
#define NT 3        // node types
#define NI 8        // intents
#define TE 256      // edges per pass1 tile
#define TILES_X 28  // blocks per relation (252 total ~ 1/CU)

using frag  = __attribute__((ext_vector_type(8))) short;
using f32x4 = __attribute__((ext_vector_type(4))) float;
using u32x4 = __attribute__((ext_vector_type(4))) unsigned int;

__device__ __forceinline__ ushort f2b(float x) {
  union { float f; uint32_t u; } v; v.f = x;
  uint32_t r = v.u + 0x7FFFu + ((v.u >> 16) & 1u);  // RNE
  return (ushort)(r >> 16);
}

// pack two f32 -> one u32 of 2xbf16 (RNE) in a single instruction
__device__ __forceinline__ uint32_t cvtpk(float lo, float hi) {
  uint32_t r;
  asm("v_cvt_pk_bf16_f32 %0, %1, %2" : "=v"(r) : "v"(lo), "v"(hi));
  return r;
}

// LDS tiles: row-major [rows][128] bf16, 16B chunks XOR-swizzled by (row&7).
__device__ __forceinline__ frag lds_rd(const ushort* b, int row, int k) {
  const int ch = ((k >> 3) ^ (row & 7));
  return *(const frag*)(b + row * D + (ch << 3));
}
__device__ __forceinline__ void lds_wr(ushort* b, int row, int ch, frag v) {
  *(frag*)(b + row * D + ((ch ^ (row & 7)) << 3)) = v;
}
__device__ __forceinline__ void lds_wr2(ushort* b, int row, int k, uint32_t v) {
  const int ch = (k >> 3) ^ (row & 7);               // k even, pair (k,k+1)
  *(uint32_t*)(b + row * D + (ch << 3) + (k & 7)) = v;
}

__global__ void k_init(ushort* __restrict__ entb, const int* __restrict__ ntypes,
                       const float* __restrict__ def, const float* __restrict__ emb) {
  int i = blockIdx.x * blockDim.x + threadIdx.x;  // one per 4 elems
  if (i >= NE * (D / 4)) return;
  int row = i >> 5, ch = i & 31;
  float4 v;
  if (row < EN) v = ((const float4*)(def + ntypes[row] * D))[ch];
  else v = ((const float4*)(emb + (size_t)(row - EN) * D))[ch];
  ushort4 h;
  h.x = f2b(v.x); h.y = f2b(v.y); h.z = f2b(v.z); h.w = f2b(v.w);
  ((ushort4*)entb)[i] = h;
}

__global__ void k_zero_cnt(int* cnt) { if (threadIdx.x < 48) cnt[threadIdx.x] = 0; }

// ---------- weights -> bf16, transposed [n][k], pre-swizzled to the LDS image ----------
__global__ __launch_bounds__(256) void k_wconv(const float* __restrict__ Wr,
                                               const float* __restrict__ Wm,
                                               ushort* __restrict__ wrelb,
                                               ushort* __restrict__ wmsgb) {
  const int nrel = NR * DR * (D / 8);   // 9216 chunks
  const int nmsg = NR * D * (D / 8);    // 18432 chunks
  int idx = blockIdx.x * 256 + threadIdx.x;
  if (idx < nrel) {
    int r = idx / (DR * 16), rem = idx % (DR * 16), n = rem / 16, sc = rem % 16;
    int kb = (sc ^ (n & 7)) * 8;
    const float* s = Wr + (size_t)r * D * DR + (size_t)kb * DR + n;
    uint4 pk;
    pk.x = cvtpk(s[0 * DR], s[1 * DR]); pk.y = cvtpk(s[2 * DR], s[3 * DR]);
    pk.z = cvtpk(s[4 * DR], s[5 * DR]); pk.w = cvtpk(s[6 * DR], s[7 * DR]);
    *(uint4*)(wrelb + (size_t)r * DR * D + n * D + sc * 8) = pk;
  } else if (idx < nrel + nmsg) {
    int j = idx - nrel;
    int r = j / (D * 16), rem = j % (D * 16), n = rem / 16, sc = rem % 16;
    int kb = (sc ^ (n & 7)) * 8;
    const float* s = Wm + (size_t)r * D * D + (size_t)kb * D + n;
    uint4 pk;
    pk.x = cvtpk(s[0 * D], s[1 * D]); pk.y = cvtpk(s[2 * D], s[3 * D]);
    pk.z = cvtpk(s[4 * D], s[5 * D]); pk.w = cvtpk(s[6 * D], s[7 * D]);
    *(uint4*)(wmsgb + (size_t)r * D * D + n * D + sc * 8) = pk;
  }
}

// ---------- fused histograms ----------
__global__ __launch_bounds__(256) void k_hist2(const int* __restrict__ nedg,
                                               const int* __restrict__ sedg,
                                               int* __restrict__ cnt,
                                               int* __restrict__ thist) {
  __shared__ int h[NR];
  if (threadIdx.x < NR) h[threadIdx.x] = 0;
  __syncthreads();
  int e = blockIdx.x * 256 + threadIdx.x;
  if (e < ET) {
    const int* p = (e < EN) ? nedg + (size_t)e * 5 : sedg + (size_t)(e - EN) * 5;
    atomicAdd(&h[p[4]], 1);
    atomicAdd(&thist[p[2]], 1);
  }
  __syncthreads();
  if (threadIdx.x < NR && h[threadIdx.x]) atomicAdd(&cnt[threadIdx.x], h[threadIdx.x]);
}

__global__ void k_prefix(const int* __restrict__ cnt, int* __restrict__ base,
                         int* __restrict__ head) {
  if (threadIdx.x == 0) {
    int acc = 0;
    for (int r = 0; r < NR; r++) { base[r] = acc; head[r] = acc; acc += cnt[r]; }
  }
}

// ---------- target prefix scan ----------
__global__ __launch_bounds__(256) void k_scan1(const int* __restrict__ hist,
                                               int* __restrict__ local_ex,
                                               int* __restrict__ bsum, int n) {
  __shared__ int s[256];
  int i = blockIdx.x * 256 + threadIdx.x;
  int v = (i < n) ? hist[i] : 0;
  s[threadIdx.x] = v;
  __syncthreads();
  for (int off = 1; off < 256; off <<= 1) {
    int t = (threadIdx.x >= off) ? s[threadIdx.x - off] : 0;
    __syncthreads();
    s[threadIdx.x] += t;
    __syncthreads();
  }
  if (i < n) local_ex[i] = s[threadIdx.x] - v;
  if (threadIdx.x == 255) bsum[blockIdx.x] = s[255];
}

__global__ __launch_bounds__(512) void k_scan2(int* __restrict__ bsum, int nb) {
  __shared__ int s[512];
  int v = (threadIdx.x < nb) ? bsum[threadIdx.x] : 0;
  s[threadIdx.x] = v;
  __syncthreads();
  for (int off = 1; off < 512; off <<= 1) {
    int t = (threadIdx.x >= off) ? s[threadIdx.x - off] : 0;
    __syncthreads();
    s[threadIdx.x] += t;
    __syncthreads();
  }
  if (threadIdx.x < nb) bsum[threadIdx.x] = s[threadIdx.x] - v;
}

__global__ void k_scan3(int* __restrict__ tgt_off, const int* __restrict__ bsum,
                        int* __restrict__ thead) {
  int i = blockIdx.x * 256 + threadIdx.x;
  if (i < NE) {
    int v = tgt_off[i] + bsum[i >> 8];
    tgt_off[i] = v;
    thead[i] = v;
  }
  if (i == 0) tgt_off[NE] = ET;
}

// ---------- fused scatter: bucket-ordered epack{src, iw_index, tpos} + sequential tp2 ----------
__global__ __launch_bounds__(256) void k_scatter3(const int* __restrict__ nedg,
                                                  const int* __restrict__ sedg,
                                                  int* __restrict__ head,
                                                  int* __restrict__ thead,
                                                  int4* __restrict__ epack,
                                                  int2* __restrict__ tp2) {
  __shared__ int h[NR], bb[NR];
  if (threadIdx.x < NR) h[threadIdx.x] = 0;
  __syncthreads();
  int e = blockIdx.x * 256 + threadIdx.x;
  int r = -1, pos = 0, s = 0, t = 0, tt = 0;
  if (e < ET) {
    const int* p = (e < EN) ? nedg + (size_t)e * 5 : sedg + (size_t)(e - EN) * 5;
    s = p[0]; t = p[2]; tt = p[3]; r = p[4];
    pos = atomicAdd(&h[r], 1);
  }
  __syncthreads();
  if (threadIdx.x < NR)
    bb[threadIdx.x] = h[threadIdx.x] ? atomicAdd(&head[threadIdx.x], h[threadIdx.x]) : 0;
  __syncthreads();
  if (r >= 0) {
    int pt = atomicAdd(&thead[t], 1);
    epack[bb[r] + pos] = make_int4(s, (t * NT + tt) * NR, pt, 0);
    tp2[e] = make_int2(pt, t);   // sequential by e (coalesced)
  }
}

// ---------- per-layer dense precompute: IW[t][tt][r] for all entities ----------
__global__ __launch_bounds__(1024) void k_iw(
    const ushort* __restrict__ entb,
    const float* __restrict__ W_int, const float* __restrict__ b_int,
    const float* __restrict__ W_ibn, const float* __restrict__ b_ibn,
    float* __restrict__ IW) {
  __shared__ ushort sE[256 * D];         // 64 KB, swizzled; reused as fp32 staging
  __shared__ ushort sWi[NT * 16 * D];    // 12 KB: W_int^T, rows 8..15 zero
  __shared__ float sInt3[256 * 25];      // [row][tt*8+j], stride 25
  __shared__ float sbint[NT * NI], sWibn[NT * NI * NR], sbibn[NT * NR];

  const int tid = threadIdx.x;
  const int lane = tid & 63, wv = tid >> 6, g = lane >> 4, c = lane & 15;

  {  // two-phase W_int staging
    float a[2], b[2];
#pragma unroll
    for (int j = 0; j < 2; j++) {
      int i = tid + j * 1024;
      if (i < NT * NI * (D / 2)) {
        int tt = i / (NI * D / 2), rem = i % (NI * D / 2), jj = rem / (D / 2), k2 = rem % (D / 2);
        const float* Wi = W_int + (size_t)tt * D * NI;
        a[j] = Wi[(2 * k2) * NI + jj]; b[j] = Wi[(2 * k2 + 1) * NI + jj];
      }
    }
#pragma unroll
    for (int j = 0; j < 2; j++) {
      int i = tid + j * 1024;
      if (i < NT * NI * (D / 2)) {
        int tt = i / (NI * D / 2), rem = i % (NI * D / 2), jj = rem / (D / 2), k2 = rem % (D / 2);
        lds_wr2(sWi, tt * 16 + jj, 2 * k2, cvtpk(a[j], b[j]));
      }
    }
  }
  for (int i = tid; i < NT * 8 * (D / 2); i += 1024) {
    int tt = i / (8 * D / 2), rem = i % (8 * D / 2), j = rem / (D / 2), k2 = rem % (D / 2);
    lds_wr2(sWi, tt * 16 + 8 + j, 2 * k2, 0u);
  }
  if (tid < NT * NI) sbint[tid] = b_int[tid];
  for (int i = tid; i < NT * NI * NR; i += 1024) sWibn[i] = W_ibn[i];
  if (tid < NT * NR) sbibn[tid] = b_ibn[tid];

  const int ebase = blockIdx.x * 256;
  const int nrow = min(256, NE - ebase);
  {
    frag tmp[4];
#pragma unroll
    for (int j = 0; j < 4; j++) {
      int i = tid + j * 1024, row = i >> 4, ch = i & 15;
      tmp[j] = (row < nrow) ? ((const frag*)(entb + (size_t)(ebase + row) * D))[ch] : (frag){};
    }
#pragma unroll
    for (int j = 0; j < 4; j++) {
      int i = tid + j * 1024, row = i >> 4, ch = i & 15;
      lds_wr(sE, row, ch, tmp[j]);
    }
  }
  __syncthreads();

  {
    f32x4 accI[NT];
#pragma unroll
    for (int tt = 0; tt < NT; tt++) accI[tt] = (f32x4){0.f, 0.f, 0.f, 0.f};
#pragma unroll
    for (int ks = 0; ks < 4; ks++) {
      const int k = ks * 32 + g * 8;
      frag a = lds_rd(sE, wv * 16 + c, k);
#pragma unroll
      for (int tt = 0; tt < NT; tt++) {
        frag b = lds_rd(sWi, tt * 16 + c, k);
        accI[tt] = __builtin_amdgcn_mfma_f32_16x16x32_bf16(a, b, accI[tt], 0, 0, 0);
      }
    }
    if (c < NI) {
      const int rb = wv * 16 + g * 4;
#pragma unroll
      for (int tt = 0; tt < NT; tt++)
#pragma unroll
        for (int q = 0; q < 4; q++) sInt3[(rb + q) * 25 + tt * 8 + c] = accI[tt][q];
    }
  }
  __syncthreads();

  float* stg = (float*)sE;
  {
    const int row = tid & 255, tt = tid >> 8;
    if (tt < NT && row < nrow) {
      float it[NI], mx = -1e30f;
#pragma unroll
      for (int j = 0; j < NI; j++) {
        it[j] = sInt3[row * 25 + tt * 8 + j] + sbint[tt * NI + j];
        mx = fmaxf(mx, it[j]);
      }
      float ssum = 0.f;
#pragma unroll
      for (int j = 0; j < NI; j++) { it[j] = __expf(it[j] - mx); ssum += it[j]; }
      const float inv = 1.f / ssum;
      float qv[NR];
#pragma unroll
      for (int k = 0; k < NR; k++) qv[k] = sbibn[tt * NR + k];
#pragma unroll
      for (int j = 0; j < NI; j++) {
        const float ij = it[j] * inv;
#pragma unroll
        for (int k = 0; k < NR; k++) qv[k] = fmaf(ij, sWibn[(tt * NI + j) * NR + k], qv[k]);
      }
      float m9 = qv[0];
#pragma unroll
      for (int k = 1; k < NR; k++) m9 = fmaxf(m9, qv[k]);
      float s9 = 0.f;
#pragma unroll
      for (int k = 0; k < NR; k++) s9 += __expf(qv[k] - m9);
      const float i9 = 1.f / s9;
#pragma unroll
      for (int k = 0; k < NR; k++) stg[row * 27 + tt * 9 + k] = __expf(qv[k] - m9) * i9;
    }
  }
  __syncthreads();

  const int n27 = nrow * 27;
  float* outp = IW + (size_t)ebase * 27;
  for (int i = tid; i < n27; i += 1024) outp[i] = stg[i];
}

// ---------- per-edge pass: epack + cross-tile register prefetch; plain (L2) stores ----------
__global__ __launch_bounds__(1024) void k_pass1(
    const ushort* __restrict__ entb,
    const int4* __restrict__ epack,
    const int* __restrict__ cnt, const int* __restrict__ base_g,
    const float* __restrict__ IW,
    const float* __restrict__ rel_emb, const float* __restrict__ b_rel,
    const ushort* __restrict__ wrelb, const ushort* __restrict__ wmsgb,
    ushort* __restrict__ msgbuf, float* __restrict__ exps_b) {
  const int r = blockIdx.y;
  __shared__ ushort sA[TE * D];          // 64 KB: src tile (bf16, swizzled)
  __shared__ ushort sWm[D * D];          // 32 KB
  __shared__ ushort sWr[DR * D];         // 16 KB
  __shared__ int sTP[TE];
  __shared__ float sIW[TE];
  __shared__ float sbrel[DR], srele[DR];

  const int tid = threadIdx.x;
  const int lane = tid & 63;
  const int wv = tid >> 6;       // 0..15
  const int g = lane >> 4;       // 0..3
  const int c = lane & 15;       // 0..15
  const int row = tid & 255, h = tid >> 8;

  // weight staging: straight b128 copies of the pre-swizzled bf16 image
  {
    const frag* wr = (const frag*)(wrelb + (size_t)r * DR * D);
    ((frag*)sWr)[tid] = wr[tid];                       // 1024 chunks exactly
    const frag* wm = (const frag*)(wmsgb + (size_t)r * D * D);
    ((frag*)sWm)[tid] = wm[tid];
    ((frag*)sWm)[tid + 1024] = wm[tid + 1024];
  }
  if (tid < DR) { sbrel[tid] = b_rel[r * DR + tid]; srele[tid] = rel_emb[r * DR + tid]; }

  const int nr = cnt[r];
  const int bbase = base_g[r];
  const int ntiles = (nr + TE - 1) / TE;

  int4 mp; frag tmp[4]; float iwv = 0.f;
  auto prefetch = [&](int t_) {
    int eidx = t_ * TE + row;
    if (eidx >= nr) eidx = 0;                          // clamp within relation
    mp = epack[bbase + eidx];
    const frag* rp = (const frag*)(entb + (size_t)mp.x * D);
#pragma unroll
    for (int j = 0; j < 4; j++) tmp[j] = rp[h * 4 + j];
    iwv = IW[mp.y + r];
  };

  int tile = blockIdx.x;
  if (tile < ntiles) prefetch(tile);

  for (; tile < ntiles; tile += gridDim.x) {
    const int ne = min(TE, nr - tile * TE);
    __syncthreads();  // prev tile's GEMM/epilogue done with sA/sTP/sIW (and staging on iter 0)

    // commit staged tile
#pragma unroll
    for (int j = 0; j < 4; j++) lds_wr(sA, row, h * 4 + j, tmp[j]);
    if (h == 0) { sTP[row] = mp.z; sIW[row] = iwv; }
    __syncthreads();

    // prefetch next tile (hides under GEMM + epilogue)
    const int nxt = tile + gridDim.x;
    if (nxt < ntiles) prefetch(nxt);

    // ---- main GEMMs ----
    f32x4 accR[4], accM[8];
#pragma unroll
    for (int nt = 0; nt < 4; nt++) accR[nt] = (f32x4){0.f, 0.f, 0.f, 0.f};
#pragma unroll
    for (int nt = 0; nt < 8; nt++) accM[nt] = (f32x4){0.f, 0.f, 0.f, 0.f};
#pragma unroll
    for (int ks = 0; ks < 4; ks++) {
      const int k = ks * 32 + g * 8;
      frag a0 = lds_rd(sA, wv * 16 + c, k);
#pragma unroll
      for (int nt = 0; nt < 4; nt++) {
        frag b = lds_rd(sWr, nt * 16 + c, k);
        accR[nt] = __builtin_amdgcn_mfma_f32_16x16x32_bf16(a0, b, accR[nt], 0, 0, 0);
      }
#pragma unroll
      for (int nt = 0; nt < 8; nt++) {
        frag b = lds_rd(sWm, nt * 16 + c, k);
        accM[nt] = __builtin_amdgcn_mfma_f32_16x16x32_bf16(a0, b, accM[nt], 0, 0, 0);
      }
    }

    const int mb = wv * 16 + g * 4;

    // ---- score epilogue (exps written SEQUENTIALLY in bucket order) ----
    float es[4];
    {
      float v[4] = {0.f, 0.f, 0.f, 0.f};
#pragma unroll
      for (int nt = 0; nt < 4; nt++) {
        const int col = nt * 16 + c;
        const float br = sbrel[col], re = srele[col];
#pragma unroll
        for (int q = 0; q < 4; q++) {
          const float x = accR[nt][q] + br;
          const float sl = x > 0.f ? 1.0507009873554805f * x
                                   : 1.7580993408473766f * (__expf(x) - 1.f);
          v[q] = fmaf(sl, re, v[q]);
        }
      }
#pragma unroll
      for (int off = 1; off < 16; off <<= 1)
#pragma unroll
        for (int q = 0; q < 4; q++) v[q] += __shfl_xor(v[q], off, 64);
#pragma unroll
      for (int q = 0; q < 4; q++) {
        const int m = mb + q;
        es[q] = __expf(v[q] * sIW[m]);
        if (c == 0 && m < ne) exps_b[bbase + tile * TE + m] = es[q];
      }
    }

    // ---- msg write: plain stores (L2 write-combining assembles full lines) ----
    {
#pragma unroll
      for (int q = 0; q < 4; q++) {
        const int m = mb + q;
        ushort* mrow = msgbuf + (size_t)sTP[m] * D;
#pragma unroll
        for (int nt = 0; nt < 8; nt++) {
          float val = accM[nt][q] * es[q];
          float other = __shfl_xor(val, 1, 64);
          if (!(c & 1) && m < ne)
            *(uint32_t*)(mrow + nt * 16 + c) = cvtpk(val, other);
        }
      }
    }
  }
}

// ---------- permute exps: bucket order -> target-sorted order (1MB, L2-resident) ----------
__global__ __launch_bounds__(256) void k_perm(const int4* __restrict__ epack,
                                              const float* __restrict__ exps_b,
                                              float* __restrict__ exps_s) {
  int i = blockIdx.x * 256 + threadIdx.x;
  if (i < ET) exps_s[epack[i].z] = exps_b[i];
}

// ---------- per-target reduce: NT msgbuf loads; writes ent + drec (both coalesced) ----------
__global__ __launch_bounds__(256) void k_agg(
    const ushort* __restrict__ msgbuf, const float* __restrict__ exps_s,
    const int* __restrict__ tgt_off,
    ushort* __restrict__ entb, float* __restrict__ fout,
    float* __restrict__ drec, int last) {
  const int lg = threadIdx.x & 15;
  const int grp = threadIdx.x >> 4;
  const int ngrp = gridDim.x * 16;
  for (int t = blockIdx.x * 16 + grp; t < NE; t += ngrp) {
    const int beg = tgt_off[t], end = tgt_off[t + 1];
    float a[8] = {0.f, 0.f, 0.f, 0.f, 0.f, 0.f, 0.f, 0.f};
    float dsum = 0.f;
    for (int j = beg; j < end; j++) {
      const u32x4 pk = __builtin_nontemporal_load((const u32x4*)(msgbuf + (size_t)j * D + lg * 8));
      dsum += exps_s[j];
      a[0] += __uint_as_float(pk.x << 16); a[1] += __uint_as_float(pk.x & 0xFFFF0000u);
      a[2] += __uint_as_float(pk.y << 16); a[3] += __uint_as_float(pk.y & 0xFFFF0000u);
      a[4] += __uint_as_float(pk.z << 16); a[5] += __uint_as_float(pk.z & 0xFFFF0000u);
      a[6] += __uint_as_float(pk.w << 16); a[7] += __uint_as_float(pk.w & 0xFFFF0000u);
    }
    const float rec = (dsum != 0.f) ? 1.f / dsum : 0.f;
    if (lg == 0) drec[t] = rec;
#pragma unroll
    for (int i = 0; i < 8; i++) a[i] *= rec;
    if (last) {
      float4* o = (float4*)(fout + (size_t)t * D + lg * 8);
      o[0] = make_float4(a[0], a[1], a[2], a[3]);
      o[1] = make_float4(a[4], a[5], a[6], a[7]);
    } else {
      uint4 pk;
      pk.x = (uint32_t)f2b(a[0]) | ((uint32_t)f2b(a[1]) << 16);
      pk.y = (uint32_t)f2b(a[2]) | ((uint32_t)f2b(a[3]) << 16);
      pk.z = (uint32_t)f2b(a[4]) | ((uint32_t)f2b(a[5]) << 16);
      pk.w = (uint32_t)f2b(a[6]) | ((uint32_t)f2b(a[7]) << 16);
      *(uint4*)(entb + (size_t)t * D + lg * 8) = pk;
    }
  }
}

// ---------- dist in original edge order: sequential reads of tp2, sequential writes ----------
__global__ __launch_bounds__(256) void k_dist2(const int2* __restrict__ tp2,
                                               const float* __restrict__ exps_s,
                                               const float* __restrict__ drec,
                                               float* __restrict__ dout) {
  int e = blockIdx.x * 256 + threadIdx.x;
  if (e >= ET) return;
  const int2 v = tp2[e];
  dout[e] = exps_s[v.x] * drec[v.y];
}

extern "C" void kernel_launch(void* const* d_in, const int* in_sizes, int n_in,
                              void* d_out, int out_size, void* d_ws, size_t ws_size,
                              hipStream_t stream) {
  const int* nedg = (const int*)d_in[0];
  const int* ntypes = (const int*)d_in[1];
  const int* sedg = (const int*)d_in[2];
  const float* emb = (const float*)d_in[3];
  const float* def = (const float*)d_in[4];
  const float* rel_emb = (const float*)d_in[5];
  const float* W_rel = (const float*)d_in[6];
  const float* b_rel = (const float*)d_in[7];
  const float* W_msg = (const float*)d_in[8];
  const float* W_int = (const float*)d_in[9];
  const float* b_int = (const float*)d_in[10];
  const float* W_ibn = (const float*)d_in[11];
  const float* b_ibn = (const float*)d_in[12];
  float* out = (float*)d_out;

  char* w = (char*)d_ws;
  size_t off = 0;
  ushort* entb = (ushort*)(w + off); off += (size_t)NE * D * 2;        // 25.6 MB
  ushort* msgbuf = (ushort*)(w + off); off += (size_t)ET * D * 2;      // 65.0 MB
  float* exps_s = (float*)(w + off); off += (size_t)ET * 4;
  float* exps_b = (float*)(w + off); off += (size_t)ET * 4;
  int4* epack = (int4*)(w + off); off += (size_t)ET * 16;              // 4.1 MB
  int2* tp2 = (int2*)(w + off); off += (size_t)ET * 8;                 // 2.0 MB
  int* tgt_off = (int*)(w + off); off += (size_t)(NE + 4) * 4;
  int* thead = (int*)(w + off); off += (size_t)NE * 4;
  int* thist = (int*)(w + off); off += (size_t)NE * 4;
  float* drec = (float*)(w + off); off += (size_t)NE * 4;
  int* bsum = (int*)(w + off); off += 2048;
  int* cnt = (int*)(w + off); off += 192;
  float* IW = (float*)(w + off); off += (size_t)NE * NT * NR * 4;      // 10.8 MB
  ushort* wrelb = (ushort*)(w + off); off += (size_t)NR * DR * D * 2;  // 147 KB
  ushort* wmsgb = (ushort*)(w + off); off += (size_t)NR * D * D * 2;   // 295 KB
  int* base_g = cnt + 16;
  int* head = cnt + 32;
  float* dist_base = out + (size_t)NE * D;

  const int eblocks = (ET + 255) / 256;
  const int nb = (NE + 255) / 256;  // 391 scan/iw blocks
  const int wblocks = (NR * DR * (D / 8) + NR * D * (D / 8) + 255) / 256;

  k_init<<<dim3((NE * (D / 4) + 255) / 256), 256, 0, stream>>>(entb, ntypes, def, emb);
  k_zero_cnt<<<1, 64, 0, stream>>>(cnt);
  (void)hipMemsetAsync(thist, 0, (size_t)NE * 4, stream);
  k_wconv<<<dim3(wblocks), 256, 0, stream>>>(W_rel, W_msg, wrelb, wmsgb);
  k_hist2<<<dim3(eblocks), 256, 0, stream>>>(nedg, sedg, cnt, thist);
  k_prefix<<<1, 64, 0, stream>>>(cnt, base_g, head);
  k_scan1<<<dim3(nb), 256, 0, stream>>>(thist, tgt_off, bsum, NE);
  k_scan2<<<1, 512, 0, stream>>>(bsum, nb);
  k_scan3<<<dim3(nb), 256, 0, stream>>>(tgt_off, bsum, thead);
  k_scatter3<<<dim3(eblocks), 256, 0, stream>>>(nedg, sedg, head, thead, epack, tp2);

  for (int l = 0; l < 3; l++) {
    k_iw<<<dim3(nb), 1024, 0, stream>>>(entb, W_int, b_int, W_ibn, b_ibn, IW);
    k_pass1<<<dim3(TILES_X, NR), 1024, 0, stream>>>(
        entb, epack, cnt, base_g, IW, rel_emb, b_rel, wrelb, wmsgb, msgbuf, exps_b);
    k_perm<<<dim3(eblocks), 256, 0, stream>>>(epack, exps_b, exps_s);
    k_agg<<<dim3(2048), 256, 0, stream>>>(msgbuf, exps_s, tgt_off, entb, out, drec, l == 2);
    k_dist2<<<dim3(eblocks), 256, 0, stream>>>(tp2, exps_s, drec,
                                               dist_base + (size_t)l * ET);
  }
}